// Round 1
// baseline (133.886 us; speedup 1.0000x reference)
//
#include <hip/hip_runtime.h>
#include <hip/hip_bf16.h>

#define BM 64
#define BN 64
#define BK 32

// ---------------------------------------------------------------------------
// Edge-index layout detection: reference dtype is int64; harness may pass
// int32. If int64 (values < 2^31), every odd int32 word is 0.
// flag == 1  => int32 layout, flag == 0 => int64 layout.
// ---------------------------------------------------------------------------
__global__ void detect_i64_kernel(const int* __restrict__ e, int E, int* __restrict__ flag) {
    int i = blockIdx.x * blockDim.x + threadIdx.x;
    int acc = 0;
    for (; i < E; i += gridDim.x * blockDim.x) acc |= e[2 * i + 1];
    if (acc) atomicOr(flag, 1);
}

// Scatter edges into dense row-major bitmask [N][N/32]. atomicOr dedups.
__global__ void scatter_edges_kernel(const int* __restrict__ e, int E, int N,
                                     unsigned* __restrict__ mask,
                                     const int* __restrict__ flag) {
    bool i32mode = (*flag != 0);
    int i = blockIdx.x * blockDim.x + threadIdx.x;
    int nw = N >> 5;
    for (; i < E; i += gridDim.x * blockDim.x) {
        int row, col;
        if (i32mode) { row = e[i];         col = e[E + i]; }
        else         { row = e[2 * i];     col = e[2 * E + 2 * i]; }
        if ((unsigned)row < (unsigned)N && (unsigned)col < (unsigned)N)
            atomicOr(&mask[(size_t)row * nw + (col >> 5)], 1u << (col & 31));
    }
}

// ---------------------------------------------------------------------------
// fp32 GEMM-NT body: C[m, n] = sum_k A'[m,k] * W[n,k] + bias[n]
// A' is the virtual concat [A | A2] split at k=256 (both row stride 256).
// LDS tiles stored k-major (As[k][m]) so inner loop does float4 LDS reads.
// ---------------------------------------------------------------------------
__device__ __forceinline__ void gemm_body(
    const float* __restrict__ A, const float* __restrict__ A2,
    const float* __restrict__ W, const float* __restrict__ bias,
    float* __restrict__ C, int m0, int n0, int K, int ldw)
{
    __shared__ float As[BK][BM + 4];
    __shared__ float Bs[BK][BN + 4];
    int t  = threadIdx.x;
    int tx = t & 15;     // output col group (4 cols)
    int ty = t >> 4;     // output row group (4 rows)
    float acc[4][4] = {{0.f}};

    for (int k0 = 0; k0 < K; k0 += BK) {
        const float* Ap = (k0 < 256) ? A : A2;
        int kc = k0 & 255;
        #pragma unroll
        for (int i = 0; i < 2; i++) {
            int idx = t + i * 256;          // 0..511 float4 slots
            int r   = idx >> 3;             // 0..63 row in tile
            int c   = (idx & 7) << 2;       // 0..28 k offset
            float4 a  = *(const float4*)&Ap[(size_t)(m0 + r) * 256 + kc + c];
            As[c + 0][r] = a.x;  As[c + 1][r] = a.y;
            As[c + 2][r] = a.z;  As[c + 3][r] = a.w;
            float4 w4 = *(const float4*)&W[(size_t)(n0 + r) * ldw + k0 + c];
            Bs[c + 0][r] = w4.x; Bs[c + 1][r] = w4.y;
            Bs[c + 2][r] = w4.z; Bs[c + 3][r] = w4.w;
        }
        __syncthreads();
        #pragma unroll
        for (int kk = 0; kk < BK; kk++) {
            float4 a4 = *(const float4*)&As[kk][ty << 2];
            float4 b4 = *(const float4*)&Bs[kk][tx << 2];
            float av[4] = {a4.x, a4.y, a4.z, a4.w};
            float bw[4] = {b4.x, b4.y, b4.z, b4.w};
            #pragma unroll
            for (int i = 0; i < 4; i++)
                #pragma unroll
                for (int j = 0; j < 4; j++)
                    acc[i][j] = fmaf(av[i], bw[j], acc[i][j]);
        }
        __syncthreads();
    }

    #pragma unroll
    for (int i = 0; i < 4; i++) {
        int row  = m0 + (ty << 2) + i;
        int colb = n0 + (tx << 2);
        float4 o;
        o.x = acc[i][0] + bias[colb + 0];
        o.y = acc[i][1] + bias[colb + 1];
        o.z = acc[i][2] + bias[colb + 2];
        o.w = acc[i][3] + bias[colb + 3];
        *(float4*)&C[(size_t)row * 256 + colb] = o;
    }
}

__global__ __launch_bounds__(256) void qkv_gemm_kernel(
    const float* __restrict__ x,
    const float* __restrict__ Wq, const float* __restrict__ bq,
    const float* __restrict__ Wk, const float* __restrict__ bk,
    const float* __restrict__ Wv, const float* __restrict__ bv,
    float* __restrict__ q, float* __restrict__ k, float* __restrict__ v)
{
    int by = blockIdx.y;
    int which = by >> 2;                 // 0=q 1=k 2=v
    int n0 = (by & 3) * BN;
    const float* W = (which == 0) ? Wq : (which == 1) ? Wk : Wv;
    const float* b = (which == 0) ? bq : (which == 1) ? bk : bv;
    float*       C = (which == 0) ? q  : (which == 1) ? k  : v;
    gemm_body(x, x, W, b, C, blockIdx.x * BM, n0, 256, 256);
}

__global__ __launch_bounds__(256) void final_gemm_kernel(
    const float* __restrict__ x, const float* __restrict__ y,
    const float* __restrict__ Wp, const float* __restrict__ bp,
    float* __restrict__ out)
{
    gemm_body(x, y, Wp, bp, out, blockIdx.x * BM, blockIdx.y * BN, 512, 512);
}

// ---------------------------------------------------------------------------
// Sparse masked attention: one block per query row n.
// Stage 1: compact set bits of mask row into sorted LDS column list
//          (deterministic popcount prefix scan, no atomics).
// Stage 2: 8 head-groups x 32 lanes; online softmax over neighbors.
// ---------------------------------------------------------------------------
__global__ __launch_bounds__(256) void attn_kernel(
    const unsigned* __restrict__ mask,
    const float* __restrict__ q, const float* __restrict__ k,
    const float* __restrict__ v, float* __restrict__ y, int N)
{
    __shared__ int cols[4096];
    __shared__ int wc[128];
    int n = blockIdx.x;
    int t = threadIdx.x;
    int nw = N >> 5;                       // mask words per row (<=128)

    unsigned word = 0;
    if (t < 128) {
        word = (t < nw) ? mask[(size_t)n * nw + t] : 0u;
        wc[t] = __popc(word);
    }
    __syncthreads();
    // Hillis-Steele inclusive scan over 128 counts
    for (int off = 1; off < 128; off <<= 1) {
        int val = 0;
        if (t < 128) { val = wc[t]; if (t >= off) val += wc[t - off]; }
        __syncthreads();
        if (t < 128) wc[t] = val;
        __syncthreads();
    }
    if (t < 128) {
        int off = wc[t] - __popc(word);    // exclusive offset
        unsigned w = word;
        while (w) {
            int b = __ffs(w) - 1;
            w &= w - 1;
            cols[off++] = t * 32 + b;
        }
    }
    __syncthreads();
    int cnt = wc[127];

    // t = h*32 + d, so every global address is row*256 + t (fully coalesced)
    const float scale = 0.17677669529663687f;  // 1/sqrt(32)
    float qv  = q[(size_t)n * 256 + t];
    float mx  = -1e30f, l = 0.f, acc = 0.f;
    for (int j = 0; j < cnt; j++) {
        int m = cols[j];
        float p = qv * k[(size_t)m * 256 + t];
        #pragma unroll
        for (int o = 16; o > 0; o >>= 1) p += __shfl_xor(p, o, 32);
        float s = p * scale;
        float mnew = fmaxf(mx, s);
        float f = __expf(mx - mnew);
        float w = __expf(s - mnew);
        float vv = v[(size_t)m * 256 + t];
        l   = l * f + w;
        acc = acc * f + w * vv;
        mx  = mnew;
    }
    y[(size_t)n * 256 + t] = (cnt > 0) ? (acc / l) : 0.f;
}

// ---------------------------------------------------------------------------
extern "C" void kernel_launch(void* const* d_in, const int* in_sizes, int n_in,
                              void* d_out, int out_size, void* d_ws, size_t ws_size,
                              hipStream_t stream) {
    const float* x  = (const float*)d_in[0];
    const int*   ei = (const int*)d_in[1];
    const float* Wq = (const float*)d_in[2];
    const float* bq = (const float*)d_in[3];
    const float* Wk = (const float*)d_in[4];
    const float* bk = (const float*)d_in[5];
    const float* Wv = (const float*)d_in[6];
    const float* bv = (const float*)d_in[7];
    const float* Wp = (const float*)d_in[8];
    const float* bp = (const float*)d_in[9];
    float* out = (float*)d_out;

    const int D = 256;
    int N = in_sizes[0] / D;       // 4096
    int E = in_sizes[1] / 2;       // 135168 edges (incl. self loops)

    size_t maskB = (size_t)N * (N >> 5) * sizeof(unsigned);   // 2 MB
    char* ws = (char*)d_ws;
    unsigned* mask = (unsigned*)ws;
    int* flag = (int*)(ws + maskB);
    float* q = (float*)(ws + maskB + 256);
    float* k = q + (size_t)N * D;
    float* v = k + (size_t)N * D;
    float* y = v + (size_t)N * D;

    hipMemsetAsync(ws, 0, maskB + 256, stream);
    detect_i64_kernel<<<256, 256, 0, stream>>>(ei, E, flag);
    scatter_edges_kernel<<<256, 256, 0, stream>>>(ei, E, N, mask, flag);

    dim3 gq(N / BM, 12);
    qkv_gemm_kernel<<<gq, 256, 0, stream>>>(x, Wq, bq, Wk, bk, Wv, bv, q, k, v);

    attn_kernel<<<N, 256, 0, stream>>>(mask, q, k, v, y, N);

    dim3 gf(N / BM, 4);
    final_gemm_kernel<<<gf, 256, 0, stream>>>(x, y, Wp, bp, out);
}